// Round 6
// baseline (2842.638 us; speedup 1.0000x reference)
//
#include <hip/hip_runtime.h>
#include <math.h>

#define HH 96
#define WW 96
#define HW 9216
#define TT 5

typedef __attribute__((ext_vector_type(8))) short bf16x8;
typedef __attribute__((ext_vector_type(4))) float f32x4;

__device__ __forceinline__ float sigf(float x) { return 1.0f / (1.0f + expf(-x)); }
__device__ __forceinline__ unsigned short bhi(float x) {
    return (unsigned short)(__float_as_uint(x) >> 16);
}
__device__ __forceinline__ unsigned short blo(float x) {
    float h = __uint_as_float(__float_as_uint(x) & 0xffff0000u);
    return (unsigned short)(__float_as_uint(x - h) >> 16);
}

// ---------------------------------------------------------------------------
// Weight expansion: src [OC][IC][9] fp32 -> dst [9][OCP][2][IC] bf16 hi/lo.
// ---------------------------------------------------------------------------
__global__ __launch_bounds__(256) void wexp3_kernel(
    const float* __restrict__ w, unsigned short* __restrict__ dst,
    int OC, int OCP, int IC)
{
    long i = (long)blockIdx.x * 256 + threadIdx.x;
    int ic = (int)(i % IC);
    long r = i / IC;
    int oc = (int)(r % OCP);
    int tap = (int)(r / OCP);
    float v = (oc < OC) ? w[((long)oc * IC + ic) * 9 + tap] : 0.f;
    long base = (((long)tap * OCP + oc) * 2) * IC + ic;
    dst[base] = bhi(v);
    dst[base + IC] = blo(v);
}

// dcn_w [128][576] -> [128][2][576]
__global__ __launch_bounds__(256) void wexp1_kernel(
    const float* __restrict__ w, unsigned short* __restrict__ dst)
{
    int i = blockIdx.x * 256 + threadIdx.x;
    int k = i % 576;
    int oc = i / 576;
    float v = w[i];
    dst[((long)oc * 2) * 576 + k] = bhi(v);
    dst[((long)oc * 2 + 1) * 576 + k] = blo(v);
}

// input [b][t][64][HW] fp32 -> xbf [(t*2+b)][p][64] bf16
__global__ __launch_bounds__(256) void xprep_kernel(
    const float* __restrict__ input, unsigned short* __restrict__ xbf)
{
    long i = (long)blockIdx.x * 256 + threadIdx.x;
    int p = (int)(i % HW);
    long r = i / HW;
    int c = (int)(r % 64);
    long bt = r / 64;
    int b = (int)(bt / TT), t = (int)(bt % TT);
    float v = input[i];
    xbf[(((long)(t * 2 + b) * HW) + p) * 64 + c] = bhi(v);
}

// ---------------------------------------------------------------------------
// MFMA implicit-GEMM 3x3 conv, software-pipelined staging.
// Block 256/4 waves; pixel tile NROWS x 16; oc tile 64. Wave grid 2x2.
// XMAP: src1 image slot = ((z<2)?t0:t1)*2 + (z&1) (x input, dir-parallel).
// OUTMODE: 0 = fp32 NCHW; 1 = fp32 NCHW + (t,b) permute; 2 = bf16 NHWC.
// ---------------------------------------------------------------------------
template<int IC, int IC1, bool S1LO, bool S2LO, int OUTMODE, int NROWS, bool XMAP>
__global__ __launch_bounds__(256) void conv3x3_v3(
    const unsigned short* __restrict__ src1, long s1stride,
    const unsigned short* __restrict__ src2, long s2stride,
    const unsigned short* __restrict__ wexp,
    const float* __restrict__ bias,
    float* __restrict__ outF, unsigned short* __restrict__ outH,
    long outStride, int OC, int t0, int t1)
{
    constexpr int NCH = IC / 32;
    constexpr int NH = NROWS / 2;
    constexpr bool ANYLO = S1LO || S2LO;
    constexpr int CST = ANYLO ? 70 : 38;
    constexpr int CELLS = (NROWS + 2) * 18;
    constexpr int SLOTS = (CELLS * 4 + 255) / 256;
    __shared__ unsigned short sX[CELLS * CST];

    const int tid  = threadIdx.x;
    const int wave = tid >> 6;
    const int lane = tid & 63;
    const int m    = lane & 15;
    const int quad = lane >> 4;
    const int wm   = wave & 1;
    const int wr   = wave >> 1;

    const int tY = blockIdx.x / 6;
    const int tX = blockIdx.x % 6;
    const int ocb = blockIdx.y * 64;
    const int OCP = gridDim.y * 64;
    const int z = blockIdx.z;
    const int imgA = XMAP ? (((z < 2) ? t0 : t1) * 2 + (z & 1)) : z;

    // ---- staging geometry (chunk-independent)
    int poff[SLOTS], ldso[SLOTS], g8_[SLOTS];
#pragma unroll
    for (int s = 0; s < SLOTS; ++s) {
        int idx = tid + s * 256;
        poff[s] = -1; ldso[s] = -1; g8_[s] = 0;
        if (idx < CELLS * 4) {
            int cell = idx >> 2, g = idx & 3;
            int row = cell / 18, col = cell - row * 18;
            int gy = tY * NROWS + row - 1;
            int gx = tX * 16 + col - 1;
            ldso[s] = cell * CST + g * 8;
            g8_[s] = g * 8;
            if (gy >= 0 && gy < HH && gx >= 0 && gx < WW) poff[s] = gy * WW + gx;
        }
    }

    bf16x8 R[2][SLOTS];
    auto loadChunk = [&](int chunk) {
        const bool isS1 = (chunk * 32 < IC1);
        const bool cHL = isS1 ? S1LO : S2LO;
        const unsigned short* sp; int C1, chloc;
        if (isS1) { sp = src1 + (long)imgA * s1stride; C1 = IC1; chloc = chunk * 32; }
        else      { sp = src2 + (long)z * s2stride; C1 = IC - IC1; chloc = chunk * 32 - IC1; }
        const int pstr = cHL ? 2 * C1 : C1;
#pragma unroll
        for (int s = 0; s < SLOTS; ++s) {
            R[0][s] = (bf16x8){0,0,0,0,0,0,0,0};
            R[1][s] = (bf16x8){0,0,0,0,0,0,0,0};
            if (poff[s] >= 0) {
                long go = (long)poff[s] * pstr + chloc + g8_[s];
                R[0][s] = *(const bf16x8*)(sp + go);
                if (ANYLO && cHL) R[1][s] = *(const bf16x8*)(sp + go + C1);
            }
        }
    };

    f32x4 acc[2][NH];
#pragma unroll
    for (int mi = 0; mi < 2; ++mi)
#pragma unroll
        for (int r = 0; r < NH; ++r) acc[mi][r] = (f32x4){0.f, 0.f, 0.f, 0.f};

    loadChunk(0);
#pragma unroll
    for (int chunk = 0; chunk < NCH; ++chunk) {
        if (chunk) __syncthreads();
        // ---- commit prefetched chunk to LDS
#pragma unroll
        for (int s = 0; s < SLOTS; ++s) {
            if (ldso[s] >= 0) {
                *(bf16x8*)&sX[ldso[s]] = R[0][s];
                if (ANYLO) *(bf16x8*)&sX[ldso[s] + 32] = R[1][s];
            }
        }
        __syncthreads();
        if (chunk + 1 < NCH) loadChunk(chunk + 1);   // overlap with MFMAs below

        const bool cHL = (chunk * 32 < IC1) ? S1LO : S2LO;
#pragma unroll
        for (int kx = 0; kx < 3; ++kx) {
            bf16x8 Bh[NH + 2], Bl[NH + 2];
#pragma unroll
            for (int r = 0; r < NH + 2; ++r) {
                int cell = (wr * NH + r) * 18 + kx + m;
                Bh[r] = *(const bf16x8*)&sX[cell * CST + quad * 8];
                if (ANYLO && cHL)
                    Bl[r] = *(const bf16x8*)&sX[cell * CST + 32 + quad * 8];
            }
            bf16x8 Ah[3][2], Al[3][2];
#pragma unroll
            for (int ky = 0; ky < 3; ++ky) {
                const int tap = ky * 3 + kx;
#pragma unroll
                for (int mi = 0; mi < 2; ++mi) {
                    const unsigned short* wp = wexp +
                        (((long)tap * OCP + ocb + (wm * 2 + mi) * 16 + m) * 2) * IC
                        + chunk * 32 + quad * 8;
                    Ah[ky][mi] = *(const bf16x8*)wp;
                    Al[ky][mi] = *(const bf16x8*)(wp + IC);
                }
            }
#pragma unroll
            for (int ky = 0; ky < 3; ++ky) {
#pragma unroll
                for (int mi = 0; mi < 2; ++mi) {
#pragma unroll
                    for (int r = 0; r < NH; ++r) {
                        acc[mi][r] = __builtin_amdgcn_mfma_f32_16x16x32_bf16(
                            Ah[ky][mi], Bh[r + ky], acc[mi][r], 0, 0, 0);
                        acc[mi][r] = __builtin_amdgcn_mfma_f32_16x16x32_bf16(
                            Al[ky][mi], Bh[r + ky], acc[mi][r], 0, 0, 0);
                        if (ANYLO && cHL)
                            acc[mi][r] = __builtin_amdgcn_mfma_f32_16x16x32_bf16(
                                Ah[ky][mi], Bl[r + ky], acc[mi][r], 0, 0, 0);
                    }
                }
            }
        }
    }

    // ---- epilogue. D: row(quad*4+reg)=oc, col(lane&15)=pixel.
    if (OUTMODE == 2) {
#pragma unroll
        for (int mi = 0; mi < 2; ++mi) {
            int ocl = ocb + (wm * 2 + mi) * 16 + quad * 4;
            float b0 = bias[ocl], b1 = bias[ocl + 1], b2 = bias[ocl + 2], b3 = bias[ocl + 3];
#pragma unroll
            for (int r = 0; r < NH; ++r) {
                int p = (tY * NROWS + wr * NH + r) * WW + tX * 16 + m;
                ushort4 hv;
                hv.x = bhi(acc[mi][r].x + b0);
                hv.y = bhi(acc[mi][r].y + b1);
                hv.z = bhi(acc[mi][r].z + b2);
                hv.w = bhi(acc[mi][r].w + b3);
                *(ushort4*)&outH[(long)z * HW * 64 + (long)p * OC + ocl] = hv;
            }
        }
    } else {
        long imgOut;
        if (OUTMODE == 1) {
            int t = z >> 1, b = z & 1;
            imgOut = (long)(b * TT + t) * outStride;
        } else {
            imgOut = (long)z * outStride;
        }
        const int gxb = tX * 16 + m;
#pragma unroll
        for (int mi = 0; mi < 2; ++mi) {
#pragma unroll
            for (int reg = 0; reg < 4; ++reg) {
                int oc = ocb + (wm * 2 + mi) * 16 + quad * 4 + reg;
                if (oc < OC) {
                    float bv = bias[oc];
#pragma unroll
                    for (int r = 0; r < NH; ++r) {
                        int gy = tY * NROWS + wr * NH + r;
                        outF[imgOut + (long)oc * HW + gy * WW + gxb] = acc[mi][r][reg] + bv;
                    }
                }
            }
        }
    }
}

// ---------------------------------------------------------------------------
// Deformable sampling over 4 (dir,b) slots.
// ---------------------------------------------------------------------------
__global__ __launch_bounds__(256) void dcn_sample_kernel(
    const float* __restrict__ h,          // [4][64][HW]
    const float* __restrict__ om,         // [4][216][HW]
    unsigned short* __restrict__ samp)    // [4][p][576]
{
    int i = blockIdx.x * 256 + threadIdx.x;   // 4*G*KK*HW
    int p = i % HW;
    int r = i / HW;
    int k = r % 9;
    int g = (r / 9) % 8;
    int zz = r / 72;
    int y = p / WW, x = p - (p / WW) * WW;
    int ky = k / 3, kx = k - ky * 3;

    const float* omb = om + (long)zz * 216 * HW;
    float offy = omb[(g * 18 + k * 2) * HW + p];
    float offx = omb[(g * 18 + k * 2 + 1) * HW + p];
    float mm = sigf(omb[(144 + g * 9 + k) * HW + p]);

    float py = (float)(y + ky - 1) + offy;
    float px = (float)(x + kx - 1) + offx;
    float y0f = floorf(py), x0f = floorf(px);
    float wy = py - y0f, wx = px - x0f;
    int y0 = (int)y0f, x0 = (int)x0f;
    int y1 = y0 + 1, x1 = x0 + 1;

    bool vy0 = (y0 >= 0) && (y0 < HH), vy1 = (y1 >= 0) && (y1 < HH);
    bool vx0 = (x0 >= 0) && (x0 < WW), vx1 = (x1 >= 0) && (x1 < WW);
    int cy0 = min(max(y0, 0), HH - 1), cy1 = min(max(y1, 0), HH - 1);
    int cx0 = min(max(x0, 0), WW - 1), cx1 = min(max(x1, 0), WW - 1);
    int i00 = cy0 * WW + cx0, i01 = cy0 * WW + cx1;
    int i10 = cy1 * WW + cx0, i11 = cy1 * WW + cx1;
    float w00 = (1.f - wy) * (1.f - wx) * ((vy0 && vx0) ? mm : 0.f);
    float w01 = (1.f - wy) * wx         * ((vy0 && vx1) ? mm : 0.f);
    float w10 = wy * (1.f - wx)         * ((vy1 && vx0) ? mm : 0.f);
    float w11 = wy * wx                 * ((vy1 && vx1) ? mm : 0.f);

    const float* hb = h + ((long)zz * 64 + g * 8) * HW;
    unsigned short* sb = samp + ((long)zz * HW + p) * 576 + (g * 8) * 9 + k;
#pragma unroll
    for (int cg = 0; cg < 8; ++cg) {
        const float* hp = hb + (long)cg * HW;
        float v = w00 * hp[i00] + w01 * hp[i01] + w10 * hp[i10] + w11 * hp[i11];
        sb[cg * 9] = bhi(v);
    }
}

// ---------------------------------------------------------------------------
// 1x1 DCN einsum, pipelined. samp [z][p][576] -> fused [z][p][2][128] hl.
// ---------------------------------------------------------------------------
__global__ __launch_bounds__(256) void conv1x1_hl(
    const unsigned short* __restrict__ samp,
    const unsigned short* __restrict__ w1,   // [128][2][576]
    const float* __restrict__ bias,
    unsigned short* __restrict__ fused)
{
    __shared__ unsigned short sX[64 * 76];
    const int tid  = threadIdx.x;
    const int wave = tid >> 6;
    const int lane = tid & 63;
    const int m    = lane & 15;
    const int quad = lane >> 4;
    const int pt = blockIdx.x;
    const int zz = blockIdx.y;

    const unsigned short* sbase = samp + (long)zz * HW * 576 + (long)pt * 64 * 576;
    const int cell0 = tid >> 3, g0 = tid & 7;
    const int cell1 = (tid + 256) >> 3, g1 = tid & 7;

    bf16x8 R0, R1;
    auto loadCB = [&](int cb) {
        R0 = *(const bf16x8*)(sbase + (long)cell0 * 576 + cb * 64 + g0 * 8);
        R1 = *(const bf16x8*)(sbase + (long)cell1 * 576 + cb * 64 + g1 * 8);
    };

    f32x4 acc[2][4];
#pragma unroll
    for (int mm = 0; mm < 2; ++mm)
#pragma unroll
        for (int nf = 0; nf < 4; ++nf) acc[mm][nf] = (f32x4){0.f, 0.f, 0.f, 0.f};

    loadCB(0);
    for (int cb = 0; cb < 9; ++cb) {
        if (cb) __syncthreads();
        *(bf16x8*)&sX[cell0 * 76 + g0 * 8] = R0;
        *(bf16x8*)&sX[cell1 * 76 + g1 * 8] = R1;
        __syncthreads();
        if (cb + 1 < 9) loadCB(cb + 1);

        bf16x8 Bv[2][4];
#pragma unroll
        for (int sub = 0; sub < 2; ++sub)
#pragma unroll
            for (int nf = 0; nf < 4; ++nf)
                Bv[sub][nf] = *(const bf16x8*)&sX[(nf * 16 + m) * 76 + sub * 32 + quad * 8];
        bf16x8 Ah[2][2], Al[2][2];
#pragma unroll
        for (int sub = 0; sub < 2; ++sub)
#pragma unroll
            for (int mm = 0; mm < 2; ++mm) {
                const unsigned short* wp = w1 + ((long)((wave * 2 + mm) * 16 + m) * 2) * 576
                                           + cb * 64 + sub * 32 + quad * 8;
                Ah[sub][mm] = *(const bf16x8*)wp;
                Al[sub][mm] = *(const bf16x8*)(wp + 576);
            }
#pragma unroll
        for (int sub = 0; sub < 2; ++sub)
#pragma unroll
            for (int mm = 0; mm < 2; ++mm)
#pragma unroll
                for (int nf = 0; nf < 4; ++nf) {
                    acc[mm][nf] = __builtin_amdgcn_mfma_f32_16x16x32_bf16(
                        Ah[sub][mm], Bv[sub][nf], acc[mm][nf], 0, 0, 0);
                    acc[mm][nf] = __builtin_amdgcn_mfma_f32_16x16x32_bf16(
                        Al[sub][mm], Bv[sub][nf], acc[mm][nf], 0, 0, 0);
                }
    }

#pragma unroll
    for (int mm = 0; mm < 2; ++mm) {
        const int mf = wave * 2 + mm;
        int ocl = mf * 16 + quad * 4;
        float b0 = bias[ocl], b1 = bias[ocl + 1], b2 = bias[ocl + 2], b3 = bias[ocl + 3];
#pragma unroll
        for (int nf = 0; nf < 4; ++nf) {
            int p = pt * 64 + nf * 16 + m;
            float v0 = fmaxf(acc[mm][nf].x + b0, 0.f);
            float v1 = fmaxf(acc[mm][nf].y + b1, 0.f);
            float v2 = fmaxf(acc[mm][nf].z + b2, 0.f);
            float v3 = fmaxf(acc[mm][nf].w + b3, 0.f);
            unsigned short* op = fused + ((long)zz * HW + p) * 256 + ocl;
            ushort4 hv, lv;
            hv.x = bhi(v0); hv.y = bhi(v1); hv.z = bhi(v2); hv.w = bhi(v3);
            lv.x = blo(v0); lv.y = blo(v1); lv.z = blo(v2); lv.w = blo(v3);
            *(ushort4*)op = hv;
            *(ushort4*)(op + 128) = lv;
        }
    }
}

// ---------------------------------------------------------------------------
// LSTM gates over 4 slots; hseq slot via per-dir t.
// ---------------------------------------------------------------------------
__global__ __launch_bounds__(256) void gates_kernel(
    const float* __restrict__ cc,        // [4][256][HW]
    float* __restrict__ h, float* __restrict__ c,   // [4][64][HW]
    unsigned short* __restrict__ hbuf,   // [4][p][128] hl
    unsigned short* __restrict__ hseq,   // [(t*2+b)][p][128]
    int t0, int t1)
{
    long i = (long)blockIdx.x * 256 + threadIdx.x;   // 4*64*HW
    int p = (int)(i % HW);
    long r = i / HW;
    int ch = (int)(r % 64);
    int zz = (int)(r / 64);
    int dir = zz >> 1, b = zz & 1;
    int t = (dir == 0) ? t0 : t1;
    const float* ccb = cc + (long)zz * 256 * HW;
    long q = (long)ch * HW + p;
    float ci = ccb[q];
    float cf = ccb[64 * HW + q];
    float co = ccb[128 * HW + q];
    float cg = ccb[192 * HW + q];
    float cold = c[i];
    float c2 = sigf(cf) * cold + sigf(ci) * tanhf(cg);
    float h2 = sigf(co) * tanhf(c2);
    c[i] = c2;
    h[i] = h2;
    unsigned short* hb = hbuf + ((long)zz * HW + p) * 128;
    hb[ch] = bhi(h2);
    hb[64 + ch] = blo(h2);
    hseq[((long)(t * 2 + b) * HW + p) * 128 + dir * 64 + ch] = bhi(h2);
}

// ---------------------------------------------------------------------------
extern "C" void kernel_launch(void* const* d_in, const int* in_sizes, int n_in,
                              void* d_out, int out_size, void* d_ws, size_t ws_size,
                              hipStream_t stream)
{
    const float* input  = (const float*)d_in[0];
    const float* fuse_w = (const float*)d_in[1];
    const float* fuse_b = (const float*)d_in[2];
    const float* om_w   = (const float*)d_in[3];
    const float* om_b   = (const float*)d_in[4];
    const float* dcn_w  = (const float*)d_in[5];
    const float* dcn_b  = (const float*)d_in[6];
    const float* conv_w = (const float*)d_in[7];
    const float* conv_b = (const float*)d_in[8];
    const float* cat_w  = (const float*)d_in[9];
    const float* cat_b  = (const float*)d_in[10];
    float* out = (float*)d_out;

    char* w = (char*)d_ws;
    size_t off = 0;
    auto alloc = [&](size_t bytes) { void* p = w + off; off += (bytes + 255) & ~(size_t)255; return p; };

    unsigned short* xbf    = (unsigned short*)alloc(10L * HW * 64 * 2);
    unsigned short* hbuf   = (unsigned short*)alloc(4L * HW * 128 * 2);
    unsigned short* comb   = (unsigned short*)alloc(4L * HW * 64 * 2);
    float*          omb    = (float*)alloc(4L * 216 * HW * 4);
    unsigned short* sampb  = (unsigned short*)alloc(4L * HW * 576 * 2);
    unsigned short* fusedb = (unsigned short*)alloc(4L * HW * 256 * 2);
    float*          ccb    = (float*)alloc(4L * 256 * HW * 4);
    float*          hb     = (float*)alloc(4L * 64 * HW * 4);
    float*          cb     = (float*)alloc(4L * 64 * HW * 4);
    unsigned short* hseqb  = (unsigned short*)alloc(10L * HW * 128 * 2);
    unsigned short* Wf = (unsigned short*)alloc(9L * 64 * 2 * 128 * 2);
    unsigned short* Wo = (unsigned short*)alloc(9L * 256 * 2 * 64 * 2);
    unsigned short* Wc = (unsigned short*)alloc(9L * 256 * 2 * 128 * 2);
    unsigned short* Wk = (unsigned short*)alloc(9L * 64 * 2 * 128 * 2);
    unsigned short* W1 = (unsigned short*)alloc(128L * 2 * 576 * 2);

    dim3 blk(256);
    wexp3_kernel<<<dim3(288), blk, 0, stream>>>(fuse_w, Wf, 64, 64, 128);
    wexp3_kernel<<<dim3(576), blk, 0, stream>>>(om_w, Wo, 216, 256, 64);
    wexp3_kernel<<<dim3(1152), blk, 0, stream>>>(conv_w, Wc, 256, 256, 128);
    wexp3_kernel<<<dim3(288), blk, 0, stream>>>(cat_w, Wk, 64, 64, 128);
    wexp1_kernel<<<dim3(288), blk, 0, stream>>>(dcn_w, W1);
    xprep_kernel<<<dim3(23040), blk, 0, stream>>>(input, xbf);

    hipMemsetAsync(hbuf, 0, 4L * HW * 128 * 2, stream);
    hipMemsetAsync(hb, 0, 4L * 64 * HW * 4, stream);
    hipMemsetAsync(cb, 0, 4L * 64 * HW * 4, stream);

    for (int s = 0; s < TT; ++s) {
        int t0 = s, t1 = TT - 1 - s;
        // fuse conv: x(single, XMAP) + h(hl) -> comb bf16 NHWC (64 ch)
        conv3x3_v3<128, 64, false, true, 2, 4, true><<<dim3(144, 1, 4), blk, 0, stream>>>(
            xbf, (long)HW * 64, hbuf, (long)HW * 128,
            Wf, fuse_b, nullptr, comb, 0, 64, t0, t1);
        // om conv: comb -> om fp32 NCHW (216 ch)
        conv3x3_v3<64, 64, false, false, 0, 4, false><<<dim3(144, 4, 4), blk, 0, stream>>>(
            comb, (long)HW * 64, comb, 0,
            Wo, om_b, omb, nullptr, 216L * HW, 216, 0, 0);
        // sampling: h, om -> samp bf16 NHWC
        dcn_sample_kernel<<<dim3(10368), blk, 0, stream>>>(hb, omb, sampb);
        // 1x1 einsum + relu -> fused hl NHWC
        conv1x1_hl<<<dim3(144, 4), blk, 0, stream>>>(sampb, W1, dcn_b, fusedb);
        // big conv: fused(hl) -> cc fp32 NCHW (256 ch)
        conv3x3_v3<128, 128, true, true, 0, 4, false><<<dim3(144, 4, 4), blk, 0, stream>>>(
            fusedb, (long)HW * 256, fusedb, 0,
            Wc, conv_b, ccb, nullptr, 256L * HW, 256, 0, 0);
        // gates
        gates_kernel<<<dim3(9216), blk, 0, stream>>>(
            ccb, hb, cb, hbuf, hseqb, t0, t1);
    }
    // cat conv: hseq (single, C=128) -> out fp32 NCHW with (t,b)->(b,t) permute
    conv3x3_v3<128, 128, false, false, 1, 4, false><<<dim3(144, 1, 10), blk, 0, stream>>>(
        hseqb, (long)HW * 128, hseqb, 0,
        Wk, cat_b, out, nullptr, 64L * HW, 64, 0, 0);
}

// Round 7
// 2154.191 us; speedup vs baseline: 1.3196x; 1.3196x over previous
//
#include <hip/hip_runtime.h>
#include <math.h>

#define HH 96
#define WW 96
#define HW 9216
#define TT 5

typedef __attribute__((ext_vector_type(8))) short bf16x8;
typedef __attribute__((ext_vector_type(4))) float f32x4;

__device__ __forceinline__ float sigf(float x) { return 1.0f / (1.0f + expf(-x)); }
__device__ __forceinline__ unsigned short bhi(float x) {
    return (unsigned short)(__float_as_uint(x) >> 16);
}
__device__ __forceinline__ unsigned short blo(float x) {
    float h = __uint_as_float(__float_as_uint(x) & 0xffff0000u);
    return (unsigned short)(__float_as_uint(x - h) >> 16);
}
__device__ __forceinline__ float b2f(unsigned short u) {
    return __uint_as_float(((unsigned)u) << 16);
}

// ---------------------------------------------------------------------------
// Weight expansion: src [OC][IC][9] fp32 -> dst [9][OCP][2][IC] bf16 hi/lo.
// ---------------------------------------------------------------------------
__global__ __launch_bounds__(256) void wexp3_kernel(
    const float* __restrict__ w, unsigned short* __restrict__ dst,
    int OC, int OCP, int IC)
{
    long i = (long)blockIdx.x * 256 + threadIdx.x;
    int ic = (int)(i % IC);
    long r = i / IC;
    int oc = (int)(r % OCP);
    int tap = (int)(r / OCP);
    float v = (oc < OC) ? w[((long)oc * IC + ic) * 9 + tap] : 0.f;
    long base = (((long)tap * OCP + oc) * 2) * IC + ic;
    dst[base] = bhi(v);
    dst[base + IC] = blo(v);
}

// dcn_w [128][576] -> [128][2][576]
__global__ __launch_bounds__(256) void wexp1_kernel(
    const float* __restrict__ w, unsigned short* __restrict__ dst)
{
    int i = blockIdx.x * 256 + threadIdx.x;
    int k = i % 576;
    int oc = i / 576;
    float v = w[i];
    dst[((long)oc * 2) * 576 + k] = bhi(v);
    dst[((long)oc * 2 + 1) * 576 + k] = blo(v);
}

// input [b][t][64][HW] fp32 -> xbf [(t*2+b)][p][64] bf16
__global__ __launch_bounds__(256) void xprep_kernel(
    const float* __restrict__ input, unsigned short* __restrict__ xbf)
{
    long i = (long)blockIdx.x * 256 + threadIdx.x;
    int p = (int)(i % HW);
    long r = i / HW;
    int c = (int)(r % 64);
    long bt = r / 64;
    int b = (int)(bt / TT), t = (int)(bt % TT);
    float v = input[i];
    xbf[(((long)(t * 2 + b) * HW) + p) * 64 + c] = bhi(v);
}

// ===========================================================================
// All conv kernels: pixel tile = 4 rows x 16 cols (64 px), halo 6x18=108 cells.
// Single-stage LDS (all IC staged once, ONE barrier before compute).
// tY = bx/6 (rows 4tY..), tX = bx%6 (cols 16tX..). Cell strides are 16B-
// aligned and == 4 mod 8 dwords -> optimal b128 bank spread.
// MFMA D-layout: row(quad*4+reg)=oc, col(m)=pixel-within-row-frag.
// ===========================================================================

// ---------------------------------------------------------------------------
// Fuse conv: x (xbf, single-plane, ic 0..63) + h (hbuf hl, ic 64..127) -> comb
// 256 thr, wave = mi (OC=64), nf 0..3. Output bf16 NHWC [z][p][64].
// ---------------------------------------------------------------------------
__global__ __launch_bounds__(256) void fuse_conv(
    const unsigned short* __restrict__ xbf,
    const unsigned short* __restrict__ hbuf,
    const unsigned short* __restrict__ Wf,   // [9][64][2][128]
    const float* __restrict__ bias,
    unsigned short* __restrict__ comb,
    int t0, int t1)
{
    __shared__ unsigned short sX[108 * 200];
    const int tid = threadIdx.x;
    const int wave = tid >> 6, lane = tid & 63;
    const int m = lane & 15, quad = lane >> 4;
    const int tY = blockIdx.x / 6, tX = blockIdx.x % 6;
    const int z = blockIdx.z;
    const int imgX = ((z < 2) ? t0 : t1) * 2 + (z & 1);

    const unsigned short* xb = xbf + (long)imgX * HW * 64;
    const unsigned short* hb = hbuf + (long)z * HW * 128;

    for (int i = tid; i < 108 * 24; i += 256) {
        int cell = i / 24, v = i - cell * 24;
        int row = cell / 18, col = cell - row * 18;
        int gy = tY * 4 + row - 1, gx = tX * 16 + col - 1;
        bool ok = (gy >= 0 && gy < HH && gx >= 0 && gx < WW);
        int p = gy * WW + gx;
        bf16x8 val = (bf16x8){0,0,0,0,0,0,0,0};
        int dst;
        if (v < 8) {
            if (ok) val = *(const bf16x8*)(xb + (long)p * 64 + v * 8);
            dst = cell * 200 + v * 8;
        } else {
            int v2 = v - 8;
            int pl = v2 >> 3, c = (v2 & 7) >> 2, g = v2 & 3;
            if (ok) val = *(const bf16x8*)(hb + (long)p * 128 + pl * 64 + c * 32 + g * 8);
            dst = cell * 200 + 64 + (c * 2 + pl) * 32 + g * 8;
        }
        *(bf16x8*)&sX[dst] = val;
    }
    __syncthreads();

    f32x4 acc[4];
#pragma unroll
    for (int nf = 0; nf < 4; ++nf) acc[nf] = (f32x4){0.f, 0.f, 0.f, 0.f};

    // x chunks (0,1): 2 products (Ah,Al x Bh)
#pragma unroll
    for (int c = 0; c < 2; ++c) {
#pragma unroll
        for (int kx = 0; kx < 3; ++kx) {
            bf16x8 B[6];
#pragma unroll
            for (int r = 0; r < 6; ++r)
                B[r] = *(const bf16x8*)&sX[(r * 18 + kx + m) * 200 + c * 32 + quad * 8];
            bf16x8 Ah[3], Al[3];
#pragma unroll
            for (int ky = 0; ky < 3; ++ky) {
                const unsigned short* wp = Wf + (((long)(ky * 3 + kx) * 64 + wave * 16 + m) * 2) * 128 + c * 32 + quad * 8;
                Ah[ky] = *(const bf16x8*)wp;
                Al[ky] = *(const bf16x8*)(wp + 128);
            }
#pragma unroll
            for (int ky = 0; ky < 3; ++ky)
#pragma unroll
                for (int nf = 0; nf < 4; ++nf) {
                    acc[nf] = __builtin_amdgcn_mfma_f32_16x16x32_bf16(Ah[ky], B[nf + ky], acc[nf], 0, 0, 0);
                    acc[nf] = __builtin_amdgcn_mfma_f32_16x16x32_bf16(Al[ky], B[nf + ky], acc[nf], 0, 0, 0);
                }
        }
    }
    // h chunks (2,3): 3 products
#pragma unroll
    for (int c = 0; c < 2; ++c) {
#pragma unroll
        for (int kx = 0; kx < 3; ++kx) {
            bf16x8 Bh[6], Bl[6];
#pragma unroll
            for (int r = 0; r < 6; ++r) {
                int base = (r * 18 + kx + m) * 200 + 64 + (c * 2) * 32 + quad * 8;
                Bh[r] = *(const bf16x8*)&sX[base];
                Bl[r] = *(const bf16x8*)&sX[base + 32];
            }
            bf16x8 Ah[3], Al[3];
#pragma unroll
            for (int ky = 0; ky < 3; ++ky) {
                const unsigned short* wp = Wf + (((long)(ky * 3 + kx) * 64 + wave * 16 + m) * 2) * 128 + (2 + c) * 32 + quad * 8;
                Ah[ky] = *(const bf16x8*)wp;
                Al[ky] = *(const bf16x8*)(wp + 128);
            }
#pragma unroll
            for (int ky = 0; ky < 3; ++ky)
#pragma unroll
                for (int nf = 0; nf < 4; ++nf) {
                    acc[nf] = __builtin_amdgcn_mfma_f32_16x16x32_bf16(Ah[ky], Bh[nf + ky], acc[nf], 0, 0, 0);
                    acc[nf] = __builtin_amdgcn_mfma_f32_16x16x32_bf16(Al[ky], Bh[nf + ky], acc[nf], 0, 0, 0);
                    acc[nf] = __builtin_amdgcn_mfma_f32_16x16x32_bf16(Ah[ky], Bl[nf + ky], acc[nf], 0, 0, 0);
                }
        }
    }

    int ocl = wave * 16 + quad * 4;
    float b0 = bias[ocl], b1 = bias[ocl + 1], b2 = bias[ocl + 2], b3 = bias[ocl + 3];
#pragma unroll
    for (int nf = 0; nf < 4; ++nf) {
        int p = (tY * 4 + nf) * WW + tX * 16 + m;
        ushort4 hv;
        hv.x = bhi(acc[nf].x + b0); hv.y = bhi(acc[nf].y + b1);
        hv.z = bhi(acc[nf].z + b2); hv.w = bhi(acc[nf].w + b3);
        *(ushort4*)&comb[((long)z * HW + p) * 64 + ocl] = hv;
    }
}

// ---------------------------------------------------------------------------
// om conv: comb (single, IC=64) -> om fp32 NCHW (216 of 256 oc).
// 512 thr, wave w: mi {2w,2w+1}, nf 0..3.
// ---------------------------------------------------------------------------
__global__ __launch_bounds__(512) void om_conv(
    const unsigned short* __restrict__ comb,
    const unsigned short* __restrict__ Wo,   // [9][256][2][64]
    const float* __restrict__ bias,
    float* __restrict__ om)                  // [z][216][HW]
{
    __shared__ unsigned short sX[108 * 72];
    const int tid = threadIdx.x;
    const int wave = tid >> 6, lane = tid & 63;
    const int m = lane & 15, quad = lane >> 4;
    const int tY = blockIdx.x / 6, tX = blockIdx.x % 6;
    const int z = blockIdx.z;
    const unsigned short* cbp = comb + (long)z * HW * 64;

    for (int i = tid; i < 108 * 8; i += 512) {
        int cell = i >> 3, v = i & 7;
        int row = cell / 18, col = cell - row * 18;
        int gy = tY * 4 + row - 1, gx = tX * 16 + col - 1;
        bf16x8 val = (bf16x8){0,0,0,0,0,0,0,0};
        if (gy >= 0 && gy < HH && gx >= 0 && gx < WW)
            val = *(const bf16x8*)(cbp + (long)(gy * WW + gx) * 64 + v * 8);
        *(bf16x8*)&sX[cell * 72 + v * 8] = val;
    }
    __syncthreads();

    f32x4 acc[2][4];
#pragma unroll
    for (int mi = 0; mi < 2; ++mi)
#pragma unroll
        for (int nf = 0; nf < 4; ++nf) acc[mi][nf] = (f32x4){0.f, 0.f, 0.f, 0.f};

#pragma unroll
    for (int c = 0; c < 2; ++c) {
#pragma unroll
        for (int kx = 0; kx < 3; ++kx) {
            bf16x8 B[6];
#pragma unroll
            for (int r = 0; r < 6; ++r)
                B[r] = *(const bf16x8*)&sX[(r * 18 + kx + m) * 72 + c * 32 + quad * 8];
            bf16x8 Ah[3][2], Al[3][2];
#pragma unroll
            for (int ky = 0; ky < 3; ++ky)
#pragma unroll
                for (int mi = 0; mi < 2; ++mi) {
                    const unsigned short* wp = Wo + (((long)(ky * 3 + kx) * 256 + (wave * 2 + mi) * 16 + m) * 2) * 64 + c * 32 + quad * 8;
                    Ah[ky][mi] = *(const bf16x8*)wp;
                    Al[ky][mi] = *(const bf16x8*)(wp + 64);
                }
#pragma unroll
            for (int ky = 0; ky < 3; ++ky)
#pragma unroll
                for (int mi = 0; mi < 2; ++mi)
#pragma unroll
                    for (int nf = 0; nf < 4; ++nf) {
                        acc[mi][nf] = __builtin_amdgcn_mfma_f32_16x16x32_bf16(Ah[ky][mi], B[nf + ky], acc[mi][nf], 0, 0, 0);
                        acc[mi][nf] = __builtin_amdgcn_mfma_f32_16x16x32_bf16(Al[ky][mi], B[nf + ky], acc[mi][nf], 0, 0, 0);
                    }
        }
    }

#pragma unroll
    for (int mi = 0; mi < 2; ++mi) {
#pragma unroll
        for (int reg = 0; reg < 4; ++reg) {
            int oc = (wave * 2 + mi) * 16 + quad * 4 + reg;
            if (oc < 216) {
                float bv = bias[oc];
#pragma unroll
                for (int nf = 0; nf < 4; ++nf) {
                    int p = (tY * 4 + nf) * WW + tX * 16 + m;
                    om[((long)z * 216 + oc) * HW + p] = acc[mi][nf][reg] + bv;
                }
            }
        }
    }
}

// ---------------------------------------------------------------------------
// Deformable sampling: h from hbuf (hl NHWC), om fp32 NCHW -> samp bf16 NHWC.
// ---------------------------------------------------------------------------
__global__ __launch_bounds__(256) void dcn_sample_kernel(
    const unsigned short* __restrict__ hbuf,  // [4][p][128]
    const float* __restrict__ om,             // [4][216][HW]
    unsigned short* __restrict__ samp)        // [4][p][576]
{
    int i = blockIdx.x * 256 + threadIdx.x;   // 4*G*KK*HW
    int p = i % HW;
    int r = i / HW;
    int k = r % 9;
    int g = (r / 9) % 8;
    int zz = r / 72;
    int y = p / WW, x = p - (p / WW) * WW;
    int ky = k / 3, kx = k - ky * 3;

    const float* omb = om + (long)zz * 216 * HW;
    float offy = omb[(g * 18 + k * 2) * HW + p];
    float offx = omb[(g * 18 + k * 2 + 1) * HW + p];
    float mm = sigf(omb[(144 + g * 9 + k) * HW + p]);

    float py = (float)(y + ky - 1) + offy;
    float px = (float)(x + kx - 1) + offx;
    float y0f = floorf(py), x0f = floorf(px);
    float wy = py - y0f, wx = px - x0f;
    int y0 = (int)y0f, x0 = (int)x0f;
    int y1 = y0 + 1, x1 = x0 + 1;

    bool vy0 = (y0 >= 0) && (y0 < HH), vy1 = (y1 >= 0) && (y1 < HH);
    bool vx0 = (x0 >= 0) && (x0 < WW), vx1 = (x1 >= 0) && (x1 < WW);
    int cy0 = min(max(y0, 0), HH - 1), cy1 = min(max(y1, 0), HH - 1);
    int cx0 = min(max(x0, 0), WW - 1), cx1 = min(max(x1, 0), WW - 1);
    long i00 = cy0 * WW + cx0, i01 = cy0 * WW + cx1;
    long i10 = cy1 * WW + cx0, i11 = cy1 * WW + cx1;
    float w00 = (1.f - wy) * (1.f - wx) * ((vy0 && vx0) ? mm : 0.f);
    float w01 = (1.f - wy) * wx         * ((vy0 && vx1) ? mm : 0.f);
    float w10 = wy * (1.f - wx)         * ((vy1 && vx0) ? mm : 0.f);
    float w11 = wy * wx                 * ((vy1 && vx1) ? mm : 0.f);

    const unsigned short* hzb = hbuf + (long)zz * HW * 128 + g * 8;
    bf16x8 h00 = *(const bf16x8*)(hzb + i00 * 128);
    bf16x8 l00 = *(const bf16x8*)(hzb + i00 * 128 + 64);
    bf16x8 h01 = *(const bf16x8*)(hzb + i01 * 128);
    bf16x8 l01 = *(const bf16x8*)(hzb + i01 * 128 + 64);
    bf16x8 h10 = *(const bf16x8*)(hzb + i10 * 128);
    bf16x8 l10 = *(const bf16x8*)(hzb + i10 * 128 + 64);
    bf16x8 h11 = *(const bf16x8*)(hzb + i11 * 128);
    bf16x8 l11 = *(const bf16x8*)(hzb + i11 * 128 + 64);

    unsigned short* sb = samp + ((long)zz * HW + p) * 576 + (g * 8) * 9 + k;
#pragma unroll
    for (int cg = 0; cg < 8; ++cg) {
        float v00 = b2f((unsigned short)h00[cg]) + b2f((unsigned short)l00[cg]);
        float v01 = b2f((unsigned short)h01[cg]) + b2f((unsigned short)l01[cg]);
        float v10 = b2f((unsigned short)h10[cg]) + b2f((unsigned short)l10[cg]);
        float v11 = b2f((unsigned short)h11[cg]) + b2f((unsigned short)l11[cg]);
        float v = w00 * v00 + w01 * v01 + w10 * v10 + w11 * v11;
        sb[cg * 9] = bhi(v);
    }
}

// ---------------------------------------------------------------------------
// 1x1 DCN einsum (pipelined, unchanged structure).
// ---------------------------------------------------------------------------
__global__ __launch_bounds__(256) void conv1x1_hl(
    const unsigned short* __restrict__ samp,
    const unsigned short* __restrict__ w1,   // [128][2][576]
    const float* __restrict__ bias,
    unsigned short* __restrict__ fused)      // [z][p][256] (hi 0..127, lo 128..255)
{
    __shared__ unsigned short sX[64 * 76];
    const int tid  = threadIdx.x;
    const int wave = tid >> 6, lane = tid & 63;
    const int m = lane & 15, quad = lane >> 4;
    const int pt = blockIdx.x;
    const int zz = blockIdx.y;

    const unsigned short* sbase = samp + (long)zz * HW * 576 + (long)pt * 64 * 576;
    const int cell0 = tid >> 3, g0 = tid & 7;
    const int cell1 = (tid + 256) >> 3, g1 = tid & 7;

    bf16x8 R0, R1;
    auto loadCB = [&](int cb) {
        R0 = *(const bf16x8*)(sbase + (long)cell0 * 576 + cb * 64 + g0 * 8);
        R1 = *(const bf16x8*)(sbase + (long)cell1 * 576 + cb * 64 + g1 * 8);
    };

    f32x4 acc[2][4];
#pragma unroll
    for (int mm = 0; mm < 2; ++mm)
#pragma unroll
        for (int nf = 0; nf < 4; ++nf) acc[mm][nf] = (f32x4){0.f, 0.f, 0.f, 0.f};

    loadCB(0);
    for (int cb = 0; cb < 9; ++cb) {
        if (cb) __syncthreads();
        *(bf16x8*)&sX[cell0 * 76 + g0 * 8] = R0;
        *(bf16x8*)&sX[cell1 * 76 + g1 * 8] = R1;
        __syncthreads();
        if (cb + 1 < 9) loadCB(cb + 1);

        bf16x8 Bv[2][4];
#pragma unroll
        for (int sub = 0; sub < 2; ++sub)
#pragma unroll
            for (int nf = 0; nf < 4; ++nf)
                Bv[sub][nf] = *(const bf16x8*)&sX[(nf * 16 + m) * 76 + sub * 32 + quad * 8];
        bf16x8 Ah[2][2], Al[2][2];
#pragma unroll
        for (int sub = 0; sub < 2; ++sub)
#pragma unroll
            for (int mm = 0; mm < 2; ++mm) {
                const unsigned short* wp = w1 + ((long)((wave * 2 + mm) * 16 + m) * 2) * 576
                                           + cb * 64 + sub * 32 + quad * 8;
                Ah[sub][mm] = *(const bf16x8*)wp;
                Al[sub][mm] = *(const bf16x8*)(wp + 576);
            }
#pragma unroll
        for (int sub = 0; sub < 2; ++sub)
#pragma unroll
            for (int mm = 0; mm < 2; ++mm)
#pragma unroll
                for (int nf = 0; nf < 4; ++nf) {
                    acc[mm][nf] = __builtin_amdgcn_mfma_f32_16x16x32_bf16(
                        Ah[sub][mm], Bv[sub][nf], acc[mm][nf], 0, 0, 0);
                    acc[mm][nf] = __builtin_amdgcn_mfma_f32_16x16x32_bf16(
                        Al[sub][mm], Bv[sub][nf], acc[mm][nf], 0, 0, 0);
                }
    }

#pragma unroll
    for (int mm = 0; mm < 2; ++mm) {
        int ocl = (wave * 2 + mm) * 16 + quad * 4;
        float b0 = bias[ocl], b1 = bias[ocl + 1], b2 = bias[ocl + 2], b3 = bias[ocl + 3];
#pragma unroll
        for (int nf = 0; nf < 4; ++nf) {
            int p = pt * 64 + nf * 16 + m;
            float v0 = fmaxf(acc[mm][nf].x + b0, 0.f);
            float v1 = fmaxf(acc[mm][nf].y + b1, 0.f);
            float v2 = fmaxf(acc[mm][nf].z + b2, 0.f);
            float v3 = fmaxf(acc[mm][nf].w + b3, 0.f);
            unsigned short* op = fused + ((long)zz * HW + p) * 256 + ocl;
            ushort4 hv, lv;
            hv.x = bhi(v0); hv.y = bhi(v1); hv.z = bhi(v2); hv.w = bhi(v3);
            lv.x = blo(v0); lv.y = blo(v1); lv.z = blo(v2); lv.w = blo(v3);
            *(ushort4*)op = hv;
            *(ushort4*)(op + 128) = lv;
        }
    }
}

// ---------------------------------------------------------------------------
// Big conv (IC=128 hl, OC=256) FUSED with LSTM gates.
// 512 thr / 8 waves; wave w holds mi {w, w+8} (so ci+co / cf+cg pair in-wave).
// Epilogue: waves 4-7 stash cf/cg in LDS; waves 0-3 compute gates, write
// c (fp32 NHWC), hbuf (hl NHWC), hseq slot (bf16).
// ---------------------------------------------------------------------------
__global__ __launch_bounds__(512) void big_conv_gates(
    const unsigned short* __restrict__ fusedb,  // [z][p][256] hl
    const unsigned short* __restrict__ Wc,      // [9][256][2][128]
    const float* __restrict__ bias,
    float* __restrict__ cst,                    // [z][p][64] fp32
    unsigned short* __restrict__ hbuf,          // [z][p][128] hl
    unsigned short* __restrict__ hseq,          // [(t*2+b)][p][128]
    int t0, int t1)
{
    __shared__ unsigned short sX[108 * 264];    // 57,024 B; reused for gate xchg
    const int tid = threadIdx.x;
    const int wave = tid >> 6, lane = tid & 63;
    const int m = lane & 15, quad = lane >> 4;
    const int tY = blockIdx.x / 6, tX = blockIdx.x % 6;
    const int z = blockIdx.z;

    const unsigned short* fb = fusedb + (long)z * HW * 256;

    for (int i = tid; i < 108 * 32; i += 512) {
        int cell = i >> 5, v = i & 31;
        int row = cell / 18, col = cell - row * 18;
        int gy = tY * 4 + row - 1, gx = tX * 16 + col - 1;
        int pl = v >> 4, c = (v & 15) >> 2, g = v & 3;
        bf16x8 val = (bf16x8){0,0,0,0,0,0,0,0};
        if (gy >= 0 && gy < HH && gx >= 0 && gx < WW)
            val = *(const bf16x8*)(fb + (long)(gy * WW + gx) * 256 + pl * 128 + c * 32 + g * 8);
        *(bf16x8*)&sX[cell * 264 + (c * 2 + pl) * 32 + g * 8] = val;
    }
    __syncthreads();

    f32x4 acc[2][4];
#pragma unroll
    for (int mi = 0; mi < 2; ++mi)
#pragma unroll
        for (int nf = 0; nf < 4; ++nf) acc[mi][nf] = (f32x4){0.f, 0.f, 0.f, 0.f};

#pragma unroll
    for (int c = 0; c < 4; ++c) {
#pragma unroll
        for (int kx = 0; kx < 3; ++kx) {
            bf16x8 Bh[6], Bl[6];
#pragma unroll
            for (int r = 0; r < 6; ++r) {
                int base = (r * 18 + kx + m) * 264 + (c * 2) * 32 + quad * 8;
                Bh[r] = *(const bf16x8*)&sX[base];
                Bl[r] = *(const bf16x8*)&sX[base + 32];
            }
            bf16x8 Ah[3][2], Al[3][2];
#pragma unroll
            for (int ky = 0; ky < 3; ++ky)
#pragma unroll
                for (int mi = 0; mi < 2; ++mi) {
                    int mig = wave + mi * 8;
                    const unsigned short* wp = Wc + (((long)(ky * 3 + kx) * 256 + mig * 16 + m) * 2) * 128 + c * 32 + quad * 8;
                    Ah[ky][mi] = *(const bf16x8*)wp;
                    Al[ky][mi] = *(const bf16x8*)(wp + 128);
                }
#pragma unroll
            for (int ky = 0; ky < 3; ++ky)
#pragma unroll
                for (int mi = 0; mi < 2; ++mi)
#pragma unroll
                    for (int nf = 0; nf < 4; ++nf) {
                        acc[mi][nf] = __builtin_amdgcn_mfma_f32_16x16x32_bf16(Ah[ky][mi], Bh[nf + ky], acc[mi][nf], 0, 0, 0);
                        acc[mi][nf] = __builtin_amdgcn_mfma_f32_16x16x32_bf16(Al[ky][mi], Bh[nf + ky], acc[mi][nf], 0, 0, 0);
                        acc[mi][nf] = __builtin_amdgcn_mfma_f32_16x16x32_bf16(Ah[ky][mi], Bl[nf + ky], acc[mi][nf], 0, 0, 0);
                    }
        }
    }

    // ---- gates epilogue ----
    float* sG = (float*)sX;                  // [2][64 px][68] fp32 = 34,816 B
    float ba0[4], ba1[4];
    {
        int oc0 = wave * 16 + quad * 4;       // ci (w<4) or cf (w>=4)
        int oc1 = (wave + 8) * 16 + quad * 4; // co (w<4) or cg (w>=4)
#pragma unroll
        for (int r = 0; r < 4; ++r) { ba0[r] = bias[oc0 + r]; ba1[r] = bias[oc1 + r]; }
    }
    __syncthreads();   // all sX reads done before overwrite
    if (wave >= 4) {
        int chb = (wave - 4) * 16 + quad * 4;
#pragma unroll
        for (int nf = 0; nf < 4; ++nf) {
            int px = nf * 16 + m;
            float* f0 = &sG[(long)px * 68 + chb];
            float* f1 = &sG[64 * 68 + (long)px * 68 + chb];
#pragma unroll
            for (int r = 0; r < 4; ++r) {
                f0[r] = acc[0][nf][r] + ba0[r];   // cf
                f1[r] = acc[1][nf][r] + ba1[r];   // cg
            }
        }
    }
    __syncthreads();
    if (wave < 4) {
        int t = (z < 2) ? t0 : t1;
        int b = z & 1, dir = z >> 1;
        int chb = wave * 16 + quad * 4;
        unsigned short* hsq = hseq + ((long)(t * 2 + b) * HW) * 128 + dir * 64;
#pragma unroll
        for (int nf = 0; nf < 4; ++nf) {
            int px = nf * 16 + m;
            int p = (tY * 4 + nf) * WW + tX * 16 + m;
            float4 cf4 = *(float4*)&sG[(long)px * 68 + chb];
            float4 cg4 = *(float4*)&sG[64 * 68 + (long)px * 68 + chb];
            float* cp = &cst[((long)z * HW + p) * 64 + chb];
            float4 cold = *(float4*)cp;
            float cfv[4] = {cf4.x, cf4.y, cf4.z, cf4.w};
            float cgv[4] = {cg4.x, cg4.y, cg4.z, cg4.w};
            float coldv[4] = {cold.x, cold.y, cold.z, cold.w};
            float c2v[4], h2v[4];
#pragma unroll
            for (int r = 0; r < 4; ++r) {
                float civ = acc[0][nf][r] + ba0[r];
                float cov = acc[1][nf][r] + ba1[r];
                float c2 = sigf(cfv[r]) * coldv[r] + sigf(civ) * tanhf(cgv[r]);
                float h2 = sigf(cov) * tanhf(c2);
                c2v[r] = c2; h2v[r] = h2;
            }
            *(float4*)cp = (float4){c2v[0], c2v[1], c2v[2], c2v[3]};
            unsigned short* hp = hbuf + ((long)z * HW + p) * 128 + chb;
            ushort4 hv = {bhi(h2v[0]), bhi(h2v[1]), bhi(h2v[2]), bhi(h2v[3])};
            ushort4 lv = {blo(h2v[0]), blo(h2v[1]), blo(h2v[2]), blo(h2v[3])};
            *(ushort4*)hp = hv;
            *(ushort4*)(hp + 64) = lv;
            *(ushort4*)&hsq[(long)p * 128 + chb] = hv;
        }
    }
}

// ---------------------------------------------------------------------------
// cat conv: hseq (single-plane, IC=128) -> out fp32 NCHW with (t,b) permute.
// 256 thr, wave = mi (OC=64), nf 0..3.
// ---------------------------------------------------------------------------
__global__ __launch_bounds__(256) void cat_conv(
    const unsigned short* __restrict__ hseq,   // [(t*2+b)][p][128]
    const unsigned short* __restrict__ Wk,     // [9][64][2][128]
    const float* __restrict__ bias,
    float* __restrict__ out)
{
    __shared__ unsigned short sX[108 * 136];
    const int tid = threadIdx.x;
    const int wave = tid >> 6, lane = tid & 63;
    const int m = lane & 15, quad = lane >> 4;
    const int tY = blockIdx.x / 6, tX = blockIdx.x % 6;
    const int img = blockIdx.z;                // t*2+b
    const unsigned short* hp = hseq + (long)img * HW * 128;

    for (int i = tid; i < 108 * 16; i += 256) {
        int cell = i >> 4, v = i & 15;
        int row = cell / 18, col = cell - row * 18;
        int gy = tY * 4 + row - 1, gx = tX * 16 + col - 1;
        bf16x8 val = (bf16x8){0,0,0,0,0,0,0,0};
        if (gy >= 0 && gy < HH && gx >= 0 && gx < WW)
            val = *(const bf16x8*)(hp + (long)(gy * WW + gx) * 128 + v * 8);
        *(bf16x8*)&sX[cell * 136 + v * 8] = val;
    }
    __syncthreads();

    f32x4 acc[4];
#pragma unroll
    for (int nf = 0; nf < 4; ++nf) acc[nf] = (f32x4){0.f, 0.f, 0.f, 0.f};

#pragma unroll
    for (int c = 0; c < 4; ++c) {
#pragma unroll
        for (int kx = 0; kx < 3; ++kx) {
            bf16x8 B[6];
#pragma unroll
            for (int r = 0; r < 6; ++r)
                B[r] = *(const bf16x8*)&sX[(r * 18 + kx + m) * 136 + c * 32 + quad * 8];
            bf16x8 Ah[3], Al[3];
#pragma unroll
            for (int ky = 0; ky < 3; ++ky) {
                const unsigned short* wp = Wk + (((long)(ky * 3 + kx) * 64 + wave * 16 + m) * 2) * 128 + c * 32 + quad * 8;
                Ah[ky] = *(const bf16x8*)wp;
                Al[ky] = *(const bf16x8*)(wp + 128);
            }
#pragma unroll
            for (int ky = 0; ky < 3; ++ky)
#pragma unroll
                for (int nf = 0; nf < 4; ++nf) {
                    acc[nf] = __builtin_amdgcn_mfma_f32_16x16x32_bf16(Ah[ky], B[nf + ky], acc[nf], 0, 0, 0);
                    acc[nf] = __builtin_amdgcn_mfma_f32_16x16x32_bf16(Al[ky], B[nf + ky], acc[nf], 0, 0, 0);
                }
        }
    }

    int t = img >> 1, b = img & 1;
    long imgOut = (long)(b * TT + t) * 64 * HW;
#pragma unroll
    for (int reg = 0; reg < 4; ++reg) {
        int oc = wave * 16 + quad * 4 + reg;
        float bv = bias[oc];
#pragma unroll
        for (int nf = 0; nf < 4; ++nf) {
            int p = (tY * 4 + nf) * WW + tX * 16 + m;
            out[imgOut + (long)oc * HW + p] = acc[nf][reg] + bv;
        }
    }
}

// ---------------------------------------------------------------------------
extern "C" void kernel_launch(void* const* d_in, const int* in_sizes, int n_in,
                              void* d_out, int out_size, void* d_ws, size_t ws_size,
                              hipStream_t stream)
{
    const float* input  = (const float*)d_in[0];
    const float* fuse_w = (const float*)d_in[1];
    const float* fuse_b = (const float*)d_in[2];
    const float* om_w   = (const float*)d_in[3];
    const float* om_b   = (const float*)d_in[4];
    const float* dcn_w  = (const float*)d_in[5];
    const float* dcn_b  = (const float*)d_in[6];
    const float* conv_w = (const float*)d_in[7];
    const float* conv_b = (const float*)d_in[8];
    const float* cat_w  = (const float*)d_in[9];
    const float* cat_b  = (const float*)d_in[10];
    float* out = (float*)d_out;

    char* w = (char*)d_ws;
    size_t off = 0;
    auto alloc = [&](size_t bytes) { void* p = w + off; off += (bytes + 255) & ~(size_t)255; return p; };

    unsigned short* xbf    = (unsigned short*)alloc(10L * HW * 64 * 2);
    unsigned short* hbuf   = (unsigned short*)alloc(4L * HW * 128 * 2);
    unsigned short* comb   = (unsigned short*)alloc(4L * HW * 64 * 2);
    float*          omb    = (float*)alloc(4L * 216 * HW * 4);
    unsigned short* sampb  = (unsigned short*)alloc(4L * HW * 576 * 2);
    unsigned short* fusedb = (unsigned short*)alloc(4L * HW * 256 * 2);
    float*          cbufs  = (float*)alloc(4L * HW * 64 * 4);
    unsigned short* hseqb  = (unsigned short*)alloc(10L * HW * 128 * 2);
    unsigned short* Wf = (unsigned short*)alloc(9L * 64 * 2 * 128 * 2);
    unsigned short* Wo = (unsigned short*)alloc(9L * 256 * 2 * 64 * 2);
    unsigned short* Wc = (unsigned short*)alloc(9L * 256 * 2 * 128 * 2);
    unsigned short* Wk = (unsigned short*)alloc(9L * 64 * 2 * 128 * 2);
    unsigned short* W1 = (unsigned short*)alloc(128L * 2 * 576 * 2);

    dim3 blk(256);
    wexp3_kernel<<<dim3(288), blk, 0, stream>>>(fuse_w, Wf, 64, 64, 128);
    wexp3_kernel<<<dim3(576), blk, 0, stream>>>(om_w, Wo, 216, 256, 64);
    wexp3_kernel<<<dim3(1152), blk, 0, stream>>>(conv_w, Wc, 256, 256, 128);
    wexp3_kernel<<<dim3(288), blk, 0, stream>>>(cat_w, Wk, 64, 64, 128);
    wexp1_kernel<<<dim3(288), blk, 0, stream>>>(dcn_w, W1);
    xprep_kernel<<<dim3(23040), blk, 0, stream>>>(input, xbf);

    hipMemsetAsync(hbuf, 0, 4L * HW * 128 * 2, stream);
    hipMemsetAsync(cbufs, 0, 4L * HW * 64 * 4, stream);

    for (int s = 0; s < TT; ++s) {
        int t0 = s, t1 = TT - 1 - s;
        fuse_conv<<<dim3(144, 1, 4), blk, 0, stream>>>(
            xbf, hbuf, Wf, fuse_b, comb, t0, t1);
        om_conv<<<dim3(144, 1, 4), dim3(512), 0, stream>>>(
            comb, Wo, om_b, omb);
        dcn_sample_kernel<<<dim3(10368), blk, 0, stream>>>(hbuf, omb, sampb);
        conv1x1_hl<<<dim3(144, 4), blk, 0, stream>>>(sampb, W1, dcn_b, fusedb);
        big_conv_gates<<<dim3(144, 1, 4), dim3(512), 0, stream>>>(
            fusedb, Wc, conv_b, cbufs, hbuf, hseqb, t0, t1);
    }
    cat_conv<<<dim3(144, 1, 10), blk, 0, stream>>>(hseqb, Wk, cat_b, out);
}

// Round 8
// 1866.235 us; speedup vs baseline: 1.5232x; 1.1543x over previous
//
#include <hip/hip_runtime.h>
#include <math.h>

#define HH 96
#define WW 96
#define HW 9216
#define TT 5

typedef __attribute__((ext_vector_type(8))) short bf16x8;
typedef __attribute__((ext_vector_type(4))) float f32x4;

__device__ __forceinline__ float sigf(float x) { return 1.0f / (1.0f + expf(-x)); }
__device__ __forceinline__ unsigned short bhi(float x) {
    return (unsigned short)(__float_as_uint(x) >> 16);
}
__device__ __forceinline__ unsigned short blo(float x) {
    float h = __uint_as_float(__float_as_uint(x) & 0xffff0000u);
    return (unsigned short)(__float_as_uint(x - h) >> 16);
}
__device__ __forceinline__ float b2f(unsigned short u) {
    return __uint_as_float(((unsigned)u) << 16);
}

// ---------------------------------------------------------------------------
// Weight expansion: src [OC][IC][9] fp32 -> dst [9][OCP][2][IC] bf16 hi/lo.
// ---------------------------------------------------------------------------
__global__ __launch_bounds__(256) void wexp3_kernel(
    const float* __restrict__ w, unsigned short* __restrict__ dst,
    int OC, int OCP, int IC)
{
    long i = (long)blockIdx.x * 256 + threadIdx.x;
    int ic = (int)(i % IC);
    long r = i / IC;
    int oc = (int)(r % OCP);
    int tap = (int)(r / OCP);
    float v = (oc < OC) ? w[((long)oc * IC + ic) * 9 + tap] : 0.f;
    long base = (((long)tap * OCP + oc) * 2) * IC + ic;
    dst[base] = bhi(v);
    dst[base + IC] = blo(v);
}

// dcn_w [128][576] (576 = c*9+k) -> [128][2][576] with K re-ordered k-major:
// dst K-slot (k*64 + c) = src (c*9 + k).
__global__ __launch_bounds__(256) void wexp1_kernel(
    const float* __restrict__ w, unsigned short* __restrict__ dst)
{
    int i = blockIdx.x * 256 + threadIdx.x;   // over 128*576 dst slots
    int slot = i % 576;                        // k*64 + c
    int oc = i / 576;
    int k = slot >> 6, c = slot & 63;
    float v = w[(long)oc * 576 + c * 9 + k];
    dst[((long)oc * 2) * 576 + slot] = bhi(v);
    dst[((long)oc * 2 + 1) * 576 + slot] = blo(v);
}

// input [b][t][64][HW] fp32 -> xbf [(t*2+b)][p][64] bf16
__global__ __launch_bounds__(256) void xprep_kernel(
    const float* __restrict__ input, unsigned short* __restrict__ xbf)
{
    long i = (long)blockIdx.x * 256 + threadIdx.x;
    int p = (int)(i % HW);
    long r = i / HW;
    int c = (int)(r % 64);
    long bt = r / 64;
    int b = (int)(bt / TT), t = (int)(bt % TT);
    float v = input[i];
    xbf[(((long)(t * 2 + b) * HW) + p) * 64 + c] = bhi(v);
}

// ===========================================================================
// Conv kernels: pixel tile 4x16 (64 px), halo 6x18=108 cells, single-stage LDS.
// ===========================================================================

// ---------------------------------------------------------------------------
// Fuse conv: x (single, ic 0..63) + h (hl, ic 64..127) -> comb bf16 NHWC.
// ---------------------------------------------------------------------------
__global__ __launch_bounds__(256) void fuse_conv(
    const unsigned short* __restrict__ xbf,
    const unsigned short* __restrict__ hbuf,
    const unsigned short* __restrict__ Wf,   // [9][64][2][128]
    const float* __restrict__ bias,
    unsigned short* __restrict__ comb,
    int t0, int t1)
{
    __shared__ unsigned short sX[108 * 200];
    const int tid = threadIdx.x;
    const int wave = tid >> 6, lane = tid & 63;
    const int m = lane & 15, quad = lane >> 4;
    const int tY = blockIdx.x / 6, tX = blockIdx.x % 6;
    const int z = blockIdx.z;
    const int imgX = ((z < 2) ? t0 : t1) * 2 + (z & 1);

    const unsigned short* xb = xbf + (long)imgX * HW * 64;
    const unsigned short* hb = hbuf + (long)z * HW * 128;

    for (int i = tid; i < 108 * 24; i += 256) {
        int cell = i / 24, v = i - cell * 24;
        int row = cell / 18, col = cell - row * 18;
        int gy = tY * 4 + row - 1, gx = tX * 16 + col - 1;
        bool ok = (gy >= 0 && gy < HH && gx >= 0 && gx < WW);
        int p = gy * WW + gx;
        bf16x8 val = (bf16x8){0,0,0,0,0,0,0,0};
        int dst;
        if (v < 8) {
            if (ok) val = *(const bf16x8*)(xb + (long)p * 64 + v * 8);
            dst = cell * 200 + v * 8;
        } else {
            int v2 = v - 8;
            int pl = v2 >> 3, c = (v2 & 7) >> 2, g = v2 & 3;
            if (ok) val = *(const bf16x8*)(hb + (long)p * 128 + pl * 64 + c * 32 + g * 8);
            dst = cell * 200 + 64 + (c * 2 + pl) * 32 + g * 8;
        }
        *(bf16x8*)&sX[dst] = val;
    }
    __syncthreads();

    f32x4 acc[4];
#pragma unroll
    for (int nf = 0; nf < 4; ++nf) acc[nf] = (f32x4){0.f, 0.f, 0.f, 0.f};

#pragma unroll
    for (int c = 0; c < 2; ++c) {
#pragma unroll
        for (int kx = 0; kx < 3; ++kx) {
            bf16x8 B[6];
#pragma unroll
            for (int r = 0; r < 6; ++r)
                B[r] = *(const bf16x8*)&sX[(r * 18 + kx + m) * 200 + c * 32 + quad * 8];
            bf16x8 Ah[3], Al[3];
#pragma unroll
            for (int ky = 0; ky < 3; ++ky) {
                const unsigned short* wp = Wf + (((long)(ky * 3 + kx) * 64 + wave * 16 + m) * 2) * 128 + c * 32 + quad * 8;
                Ah[ky] = *(const bf16x8*)wp;
                Al[ky] = *(const bf16x8*)(wp + 128);
            }
#pragma unroll
            for (int ky = 0; ky < 3; ++ky)
#pragma unroll
                for (int nf = 0; nf < 4; ++nf) {
                    acc[nf] = __builtin_amdgcn_mfma_f32_16x16x32_bf16(Ah[ky], B[nf + ky], acc[nf], 0, 0, 0);
                    acc[nf] = __builtin_amdgcn_mfma_f32_16x16x32_bf16(Al[ky], B[nf + ky], acc[nf], 0, 0, 0);
                }
        }
    }
#pragma unroll
    for (int c = 0; c < 2; ++c) {
#pragma unroll
        for (int kx = 0; kx < 3; ++kx) {
            bf16x8 Bh[6], Bl[6];
#pragma unroll
            for (int r = 0; r < 6; ++r) {
                int base = (r * 18 + kx + m) * 200 + 64 + (c * 2) * 32 + quad * 8;
                Bh[r] = *(const bf16x8*)&sX[base];
                Bl[r] = *(const bf16x8*)&sX[base + 32];
            }
            bf16x8 Ah[3], Al[3];
#pragma unroll
            for (int ky = 0; ky < 3; ++ky) {
                const unsigned short* wp = Wf + (((long)(ky * 3 + kx) * 64 + wave * 16 + m) * 2) * 128 + (2 + c) * 32 + quad * 8;
                Ah[ky] = *(const bf16x8*)wp;
                Al[ky] = *(const bf16x8*)(wp + 128);
            }
#pragma unroll
            for (int ky = 0; ky < 3; ++ky)
#pragma unroll
                for (int nf = 0; nf < 4; ++nf) {
                    acc[nf] = __builtin_amdgcn_mfma_f32_16x16x32_bf16(Ah[ky], Bh[nf + ky], acc[nf], 0, 0, 0);
                    acc[nf] = __builtin_amdgcn_mfma_f32_16x16x32_bf16(Al[ky], Bh[nf + ky], acc[nf], 0, 0, 0);
                    acc[nf] = __builtin_amdgcn_mfma_f32_16x16x32_bf16(Ah[ky], Bl[nf + ky], acc[nf], 0, 0, 0);
                }
        }
    }

    int ocl = wave * 16 + quad * 4;
    float b0 = bias[ocl], b1 = bias[ocl + 1], b2 = bias[ocl + 2], b3 = bias[ocl + 3];
#pragma unroll
    for (int nf = 0; nf < 4; ++nf) {
        int p = (tY * 4 + nf) * WW + tX * 16 + m;
        ushort4 hv;
        hv.x = bhi(acc[nf].x + b0); hv.y = bhi(acc[nf].y + b1);
        hv.z = bhi(acc[nf].z + b2); hv.w = bhi(acc[nf].w + b3);
        *(ushort4*)&comb[((long)z * HW + p) * 64 + ocl] = hv;
    }
}

// ---------------------------------------------------------------------------
// om conv: comb (single, IC=64) -> om fp32 NCHW (216 of 256 oc).
// ---------------------------------------------------------------------------
__global__ __launch_bounds__(512) void om_conv(
    const unsigned short* __restrict__ comb,
    const unsigned short* __restrict__ Wo,   // [9][256][2][64]
    const float* __restrict__ bias,
    float* __restrict__ om)                  // [z][216][HW]
{
    __shared__ unsigned short sX[108 * 72];
    const int tid = threadIdx.x;
    const int wave = tid >> 6, lane = tid & 63;
    const int m = lane & 15, quad = lane >> 4;
    const int tY = blockIdx.x / 6, tX = blockIdx.x % 6;
    const int z = blockIdx.z;
    const unsigned short* cbp = comb + (long)z * HW * 64;

    for (int i = tid; i < 108 * 8; i += 512) {
        int cell = i >> 3, v = i & 7;
        int row = cell / 18, col = cell - row * 18;
        int gy = tY * 4 + row - 1, gx = tX * 16 + col - 1;
        bf16x8 val = (bf16x8){0,0,0,0,0,0,0,0};
        if (gy >= 0 && gy < HH && gx >= 0 && gx < WW)
            val = *(const bf16x8*)(cbp + (long)(gy * WW + gx) * 64 + v * 8);
        *(bf16x8*)&sX[cell * 72 + v * 8] = val;
    }
    __syncthreads();

    f32x4 acc[2][4];
#pragma unroll
    for (int mi = 0; mi < 2; ++mi)
#pragma unroll
        for (int nf = 0; nf < 4; ++nf) acc[mi][nf] = (f32x4){0.f, 0.f, 0.f, 0.f};

#pragma unroll
    for (int c = 0; c < 2; ++c) {
#pragma unroll
        for (int kx = 0; kx < 3; ++kx) {
            bf16x8 B[6];
#pragma unroll
            for (int r = 0; r < 6; ++r)
                B[r] = *(const bf16x8*)&sX[(r * 18 + kx + m) * 72 + c * 32 + quad * 8];
            bf16x8 Ah[3][2], Al[3][2];
#pragma unroll
            for (int ky = 0; ky < 3; ++ky)
#pragma unroll
                for (int mi = 0; mi < 2; ++mi) {
                    const unsigned short* wp = Wo + (((long)(ky * 3 + kx) * 256 + (wave * 2 + mi) * 16 + m) * 2) * 64 + c * 32 + quad * 8;
                    Ah[ky][mi] = *(const bf16x8*)wp;
                    Al[ky][mi] = *(const bf16x8*)(wp + 64);
                }
#pragma unroll
            for (int ky = 0; ky < 3; ++ky)
#pragma unroll
                for (int mi = 0; mi < 2; ++mi)
#pragma unroll
                    for (int nf = 0; nf < 4; ++nf) {
                        acc[mi][nf] = __builtin_amdgcn_mfma_f32_16x16x32_bf16(Ah[ky][mi], B[nf + ky], acc[mi][nf], 0, 0, 0);
                        acc[mi][nf] = __builtin_amdgcn_mfma_f32_16x16x32_bf16(Al[ky][mi], B[nf + ky], acc[mi][nf], 0, 0, 0);
                    }
        }
    }

#pragma unroll
    for (int mi = 0; mi < 2; ++mi) {
#pragma unroll
        for (int reg = 0; reg < 4; ++reg) {
            int oc = (wave * 2 + mi) * 16 + quad * 4 + reg;
            if (oc < 216) {
                float bv = bias[oc];
#pragma unroll
                for (int nf = 0; nf < 4; ++nf) {
                    int p = (tY * 4 + nf) * WW + tX * 16 + m;
                    om[((long)z * 216 + oc) * HW + p] = acc[mi][nf][reg] + bv;
                }
            }
        }
    }
}

// ---------------------------------------------------------------------------
// Deformable sampling. Output K is k-major: samp[(z*HW+p)*576 + k*64 + c].
// Each thread writes ONE contiguous bf16x8 (16 B).
// ---------------------------------------------------------------------------
__global__ __launch_bounds__(256) void dcn_sample_kernel(
    const unsigned short* __restrict__ hbuf,  // [4][p][128] hl
    const float* __restrict__ om,             // [4][216][HW]
    unsigned short* __restrict__ samp)        // [4][p][576] k-major
{
    int i = blockIdx.x * 256 + threadIdx.x;   // 4*G*KK*HW
    int p = i % HW;
    int r = i / HW;
    int k = r % 9;
    int g = (r / 9) % 8;
    int zz = r / 72;
    int y = p / WW, x = p - (p / WW) * WW;
    int ky = k / 3, kx = k - ky * 3;

    const float* omb = om + (long)zz * 216 * HW;
    float offy = omb[(g * 18 + k * 2) * HW + p];
    float offx = omb[(g * 18 + k * 2 + 1) * HW + p];
    float mm = sigf(omb[(144 + g * 9 + k) * HW + p]);

    float py = (float)(y + ky - 1) + offy;
    float px = (float)(x + kx - 1) + offx;
    float y0f = floorf(py), x0f = floorf(px);
    float wy = py - y0f, wx = px - x0f;
    int y0 = (int)y0f, x0 = (int)x0f;
    int y1 = y0 + 1, x1 = x0 + 1;

    bool vy0 = (y0 >= 0) && (y0 < HH), vy1 = (y1 >= 0) && (y1 < HH);
    bool vx0 = (x0 >= 0) && (x0 < WW), vx1 = (x1 >= 0) && (x1 < WW);
    int cy0 = min(max(y0, 0), HH - 1), cy1 = min(max(y1, 0), HH - 1);
    int cx0 = min(max(x0, 0), WW - 1), cx1 = min(max(x1, 0), WW - 1);
    long i00 = cy0 * WW + cx0, i01 = cy0 * WW + cx1;
    long i10 = cy1 * WW + cx0, i11 = cy1 * WW + cx1;
    float w00 = (1.f - wy) * (1.f - wx) * ((vy0 && vx0) ? mm : 0.f);
    float w01 = (1.f - wy) * wx         * ((vy0 && vx1) ? mm : 0.f);
    float w10 = wy * (1.f - wx)         * ((vy1 && vx0) ? mm : 0.f);
    float w11 = wy * wx                 * ((vy1 && vx1) ? mm : 0.f);

    const unsigned short* hzb = hbuf + (long)zz * HW * 128 + g * 8;
    bf16x8 h00 = *(const bf16x8*)(hzb + i00 * 128);
    bf16x8 l00 = *(const bf16x8*)(hzb + i00 * 128 + 64);
    bf16x8 h01 = *(const bf16x8*)(hzb + i01 * 128);
    bf16x8 l01 = *(const bf16x8*)(hzb + i01 * 128 + 64);
    bf16x8 h10 = *(const bf16x8*)(hzb + i10 * 128);
    bf16x8 l10 = *(const bf16x8*)(hzb + i10 * 128 + 64);
    bf16x8 h11 = *(const bf16x8*)(hzb + i11 * 128);
    bf16x8 l11 = *(const bf16x8*)(hzb + i11 * 128 + 64);

    bf16x8 outv;
#pragma unroll
    for (int cg = 0; cg < 8; ++cg) {
        float v00 = b2f((unsigned short)h00[cg]) + b2f((unsigned short)l00[cg]);
        float v01 = b2f((unsigned short)h01[cg]) + b2f((unsigned short)l01[cg]);
        float v10 = b2f((unsigned short)h10[cg]) + b2f((unsigned short)l10[cg]);
        float v11 = b2f((unsigned short)h11[cg]) + b2f((unsigned short)l11[cg]);
        float v = w00 * v00 + w01 * v01 + w10 * v10 + w11 * v11;
        outv[cg] = (short)bhi(v);
    }
    *(bf16x8*)(samp + ((long)zz * HW + p) * 576 + k * 64 + g * 8) = outv;
}

// ---------------------------------------------------------------------------
// 1x1 DCN einsum (pipelined). K ordering is k-major to match samp/W1.
// ---------------------------------------------------------------------------
__global__ __launch_bounds__(256) void conv1x1_hl(
    const unsigned short* __restrict__ samp,
    const unsigned short* __restrict__ w1,   // [128][2][576] k-major
    const float* __restrict__ bias,
    unsigned short* __restrict__ fused)      // [z][p][256] hl
{
    __shared__ unsigned short sX[64 * 76];
    const int tid  = threadIdx.x;
    const int wave = tid >> 6, lane = tid & 63;
    const int m = lane & 15, quad = lane >> 4;
    const int pt = blockIdx.x;
    const int zz = blockIdx.y;

    const unsigned short* sbase = samp + (long)zz * HW * 576 + (long)pt * 64 * 576;
    const int cell0 = tid >> 3, g0 = tid & 7;
    const int cell1 = (tid + 256) >> 3, g1 = tid & 7;

    bf16x8 R0, R1;
    auto loadCB = [&](int cb) {
        R0 = *(const bf16x8*)(sbase + (long)cell0 * 576 + cb * 64 + g0 * 8);
        R1 = *(const bf16x8*)(sbase + (long)cell1 * 576 + cb * 64 + g1 * 8);
    };

    f32x4 acc[2][4];
#pragma unroll
    for (int mm = 0; mm < 2; ++mm)
#pragma unroll
        for (int nf = 0; nf < 4; ++nf) acc[mm][nf] = (f32x4){0.f, 0.f, 0.f, 0.f};

    loadCB(0);
    for (int cb = 0; cb < 9; ++cb) {
        if (cb) __syncthreads();
        *(bf16x8*)&sX[cell0 * 76 + g0 * 8] = R0;
        *(bf16x8*)&sX[cell1 * 76 + g1 * 8] = R1;
        __syncthreads();
        if (cb + 1 < 9) loadCB(cb + 1);

        bf16x8 Bv[2][4];
#pragma unroll
        for (int sub = 0; sub < 2; ++sub)
#pragma unroll
            for (int nf = 0; nf < 4; ++nf)
                Bv[sub][nf] = *(const bf16x8*)&sX[(nf * 16 + m) * 76 + sub * 32 + quad * 8];
        bf16x8 Ah[2][2], Al[2][2];
#pragma unroll
        for (int sub = 0; sub < 2; ++sub)
#pragma unroll
            for (int mm = 0; mm < 2; ++mm) {
                const unsigned short* wp = w1 + ((long)((wave * 2 + mm) * 16 + m) * 2) * 576
                                           + cb * 64 + sub * 32 + quad * 8;
                Ah[sub][mm] = *(const bf16x8*)wp;
                Al[sub][mm] = *(const bf16x8*)(wp + 576);
            }
#pragma unroll
        for (int sub = 0; sub < 2; ++sub)
#pragma unroll
            for (int mm = 0; mm < 2; ++mm)
#pragma unroll
                for (int nf = 0; nf < 4; ++nf) {
                    acc[mm][nf] = __builtin_amdgcn_mfma_f32_16x16x32_bf16(
                        Ah[sub][mm], Bv[sub][nf], acc[mm][nf], 0, 0, 0);
                    acc[mm][nf] = __builtin_amdgcn_mfma_f32_16x16x32_bf16(
                        Al[sub][mm], Bv[sub][nf], acc[mm][nf], 0, 0, 0);
                }
    }

#pragma unroll
    for (int mm = 0; mm < 2; ++mm) {
        int ocl = (wave * 2 + mm) * 16 + quad * 4;
        float b0 = bias[ocl], b1 = bias[ocl + 1], b2 = bias[ocl + 2], b3 = bias[ocl + 3];
#pragma unroll
        for (int nf = 0; nf < 4; ++nf) {
            int p = pt * 64 + nf * 16 + m;
            float v0 = fmaxf(acc[mm][nf].x + b0, 0.f);
            float v1 = fmaxf(acc[mm][nf].y + b1, 0.f);
            float v2 = fmaxf(acc[mm][nf].z + b2, 0.f);
            float v3 = fmaxf(acc[mm][nf].w + b3, 0.f);
            unsigned short* op = fused + ((long)zz * HW + p) * 256 + ocl;
            ushort4 hv, lv;
            hv.x = bhi(v0); hv.y = bhi(v1); hv.z = bhi(v2); hv.w = bhi(v3);
            lv.x = blo(v0); lv.y = blo(v1); lv.z = blo(v2); lv.w = blo(v3);
            *(ushort4*)op = hv;
            *(ushort4*)(op + 128) = lv;
        }
    }
}

// ---------------------------------------------------------------------------
// Big conv (IC=128 hl, OC=256) FUSED with LSTM gates.
// ---------------------------------------------------------------------------
__global__ __launch_bounds__(512) void big_conv_gates(
    const unsigned short* __restrict__ fusedb,  // [z][p][256] hl
    const unsigned short* __restrict__ Wc,      // [9][256][2][128]
    const float* __restrict__ bias,
    float* __restrict__ cst,                    // [z][p][64] fp32
    unsigned short* __restrict__ hbuf,          // [z][p][128] hl
    unsigned short* __restrict__ hseq,          // [(t*2+b)][p][128]
    int t0, int t1)
{
    __shared__ unsigned short sX[108 * 264];
    const int tid = threadIdx.x;
    const int wave = tid >> 6, lane = tid & 63;
    const int m = lane & 15, quad = lane >> 4;
    const int tY = blockIdx.x / 6, tX = blockIdx.x % 6;
    const int z = blockIdx.z;

    const unsigned short* fb = fusedb + (long)z * HW * 256;

    for (int i = tid; i < 108 * 32; i += 512) {
        int cell = i >> 5, v = i & 31;
        int row = cell / 18, col = cell - row * 18;
        int gy = tY * 4 + row - 1, gx = tX * 16 + col - 1;
        int pl = v >> 4, c = (v & 15) >> 2, g = v & 3;
        bf16x8 val = (bf16x8){0,0,0,0,0,0,0,0};
        if (gy >= 0 && gy < HH && gx >= 0 && gx < WW)
            val = *(const bf16x8*)(fb + (long)(gy * WW + gx) * 256 + pl * 128 + c * 32 + g * 8);
        *(bf16x8*)&sX[cell * 264 + (c * 2 + pl) * 32 + g * 8] = val;
    }
    __syncthreads();

    f32x4 acc[2][4];
#pragma unroll
    for (int mi = 0; mi < 2; ++mi)
#pragma unroll
        for (int nf = 0; nf < 4; ++nf) acc[mi][nf] = (f32x4){0.f, 0.f, 0.f, 0.f};

#pragma unroll
    for (int c = 0; c < 4; ++c) {
#pragma unroll
        for (int kx = 0; kx < 3; ++kx) {
            bf16x8 Bh[6], Bl[6];
#pragma unroll
            for (int r = 0; r < 6; ++r) {
                int base = (r * 18 + kx + m) * 264 + (c * 2) * 32 + quad * 8;
                Bh[r] = *(const bf16x8*)&sX[base];
                Bl[r] = *(const bf16x8*)&sX[base + 32];
            }
            bf16x8 Ah[3][2], Al[3][2];
#pragma unroll
            for (int ky = 0; ky < 3; ++ky)
#pragma unroll
                for (int mi = 0; mi < 2; ++mi) {
                    int mig = wave + mi * 8;
                    const unsigned short* wp = Wc + (((long)(ky * 3 + kx) * 256 + mig * 16 + m) * 2) * 128 + c * 32 + quad * 8;
                    Ah[ky][mi] = *(const bf16x8*)wp;
                    Al[ky][mi] = *(const bf16x8*)(wp + 128);
                }
#pragma unroll
            for (int ky = 0; ky < 3; ++ky)
#pragma unroll
                for (int mi = 0; mi < 2; ++mi)
#pragma unroll
                    for (int nf = 0; nf < 4; ++nf) {
                        acc[mi][nf] = __builtin_amdgcn_mfma_f32_16x16x32_bf16(Ah[ky][mi], Bh[nf + ky], acc[mi][nf], 0, 0, 0);
                        acc[mi][nf] = __builtin_amdgcn_mfma_f32_16x16x32_bf16(Al[ky][mi], Bh[nf + ky], acc[mi][nf], 0, 0, 0);
                        acc[mi][nf] = __builtin_amdgcn_mfma_f32_16x16x32_bf16(Ah[ky][mi], Bl[nf + ky], acc[mi][nf], 0, 0, 0);
                    }
        }
    }

    // ---- gates epilogue ----
    float* sG = (float*)sX;
    float ba0[4], ba1[4];
    {
        int oc0 = wave * 16 + quad * 4;
        int oc1 = (wave + 8) * 16 + quad * 4;
#pragma unroll
        for (int r = 0; r < 4; ++r) { ba0[r] = bias[oc0 + r]; ba1[r] = bias[oc1 + r]; }
    }
    __syncthreads();
    if (wave >= 4) {
        int chb = (wave - 4) * 16 + quad * 4;
#pragma unroll
        for (int nf = 0; nf < 4; ++nf) {
            int px = nf * 16 + m;
            float* f0 = &sG[(long)px * 68 + chb];
            float* f1 = &sG[64 * 68 + (long)px * 68 + chb];
#pragma unroll
            for (int r = 0; r < 4; ++r) {
                f0[r] = acc[0][nf][r] + ba0[r];
                f1[r] = acc[1][nf][r] + ba1[r];
            }
        }
    }
    __syncthreads();
    if (wave < 4) {
        int t = (z < 2) ? t0 : t1;
        int b = z & 1, dir = z >> 1;
        int chb = wave * 16 + quad * 4;
        unsigned short* hsq = hseq + ((long)(t * 2 + b) * HW) * 128 + dir * 64;
#pragma unroll
        for (int nf = 0; nf < 4; ++nf) {
            int px = nf * 16 + m;
            int p = (tY * 4 + nf) * WW + tX * 16 + m;
            float4 cf4 = *(float4*)&sG[(long)px * 68 + chb];
            float4 cg4 = *(float4*)&sG[64 * 68 + (long)px * 68 + chb];
            float* cp = &cst[((long)z * HW + p) * 64 + chb];
            float4 cold = *(float4*)cp;
            float cfv[4] = {cf4.x, cf4.y, cf4.z, cf4.w};
            float cgv[4] = {cg4.x, cg4.y, cg4.z, cg4.w};
            float coldv[4] = {cold.x, cold.y, cold.z, cold.w};
            float c2v[4], h2v[4];
#pragma unroll
            for (int r = 0; r < 4; ++r) {
                float civ = acc[0][nf][r] + ba0[r];
                float cov = acc[1][nf][r] + ba1[r];
                float c2 = sigf(cfv[r]) * coldv[r] + sigf(civ) * tanhf(cgv[r]);
                float h2 = sigf(cov) * tanhf(c2);
                c2v[r] = c2; h2v[r] = h2;
            }
            *(float4*)cp = (float4){c2v[0], c2v[1], c2v[2], c2v[3]};
            unsigned short* hp = hbuf + ((long)z * HW + p) * 128 + chb;
            ushort4 hv = {bhi(h2v[0]), bhi(h2v[1]), bhi(h2v[2]), bhi(h2v[3])};
            ushort4 lv = {blo(h2v[0]), blo(h2v[1]), blo(h2v[2]), blo(h2v[3])};
            *(ushort4*)hp = hv;
            *(ushort4*)(hp + 64) = lv;
            *(ushort4*)&hsq[(long)p * 128 + chb] = hv;
        }
    }
}

// ---------------------------------------------------------------------------
// cat conv: hseq (single-plane, IC=128) -> out fp32 NCHW with (t,b) permute.
// ---------------------------------------------------------------------------
__global__ __launch_bounds__(256) void cat_conv(
    const unsigned short* __restrict__ hseq,
    const unsigned short* __restrict__ Wk,     // [9][64][2][128]
    const float* __restrict__ bias,
    float* __restrict__ out)
{
    __shared__ unsigned short sX[108 * 136];
    const int tid = threadIdx.x;
    const int wave = tid >> 6, lane = tid & 63;
    const int m = lane & 15, quad = lane >> 4;
    const int tY = blockIdx.x / 6, tX = blockIdx.x % 6;
    const int img = blockIdx.z;
    const unsigned short* hp = hseq + (long)img * HW * 128;

    for (int i = tid; i < 108 * 16; i += 256) {
        int cell = i >> 4, v = i & 15;
        int row = cell / 18, col = cell - row * 18;
        int gy = tY * 4 + row - 1, gx = tX * 16 + col - 1;
        bf16x8 val = (bf16x8){0,0,0,0,0,0,0,0};
        if (gy >= 0 && gy < HH && gx >= 0 && gx < WW)
            val = *(const bf16x8*)(hp + (long)(gy * WW + gx) * 128 + v * 8);
        *(bf16x8*)&sX[cell * 136 + v * 8] = val;
    }
    __syncthreads();

    f32x4 acc[4];
#pragma unroll
    for (int nf = 0; nf < 4; ++nf) acc[nf] = (f32x4){0.f, 0.f, 0.f, 0.f};

#pragma unroll
    for (int c = 0; c < 4; ++c) {
#pragma unroll
        for (int kx = 0; kx < 3; ++kx) {
            bf16x8 B[6];
#pragma unroll
            for (int r = 0; r < 6; ++r)
                B[r] = *(const bf16x8*)&sX[(r * 18 + kx + m) * 136 + c * 32 + quad * 8];
            bf16x8 Ah[3], Al[3];
#pragma unroll
            for (int ky = 0; ky < 3; ++ky) {
                const unsigned short* wp = Wk + (((long)(ky * 3 + kx) * 64 + wave * 16 + m) * 2) * 128 + c * 32 + quad * 8;
                Ah[ky] = *(const bf16x8*)wp;
                Al[ky] = *(const bf16x8*)(wp + 128);
            }
#pragma unroll
            for (int ky = 0; ky < 3; ++ky)
#pragma unroll
                for (int nf = 0; nf < 4; ++nf) {
                    acc[nf] = __builtin_amdgcn_mfma_f32_16x16x32_bf16(Ah[ky], B[nf + ky], acc[nf], 0, 0, 0);
                    acc[nf] = __builtin_amdgcn_mfma_f32_16x16x32_bf16(Al[ky], B[nf + ky], acc[nf], 0, 0, 0);
                }
        }
    }

    int t = img >> 1, b = img & 1;
    long imgOut = (long)(b * TT + t) * 64 * HW;
#pragma unroll
    for (int reg = 0; reg < 4; ++reg) {
        int oc = wave * 16 + quad * 4 + reg;
        float bv = bias[oc];
#pragma unroll
        for (int nf = 0; nf < 4; ++nf) {
            int p = (tY * 4 + nf) * WW + tX * 16 + m;
            out[imgOut + (long)oc * HW + p] = acc[nf][reg] + bv;
        }
    }
}

// ---------------------------------------------------------------------------
extern "C" void kernel_launch(void* const* d_in, const int* in_sizes, int n_in,
                              void* d_out, int out_size, void* d_ws, size_t ws_size,
                              hipStream_t stream)
{
    const float* input  = (const float*)d_in[0];
    const float* fuse_w = (const float*)d_in[1];
    const float* fuse_b = (const float*)d_in[2];
    const float* om_w   = (const float*)d_in[3];
    const float* om_b   = (const float*)d_in[4];
    const float* dcn_w  = (const float*)d_in[5];
    const float* dcn_b  = (const float*)d_in[6];
    const float* conv_w = (const float*)d_in[7];
    const float* conv_b = (const float*)d_in[8];
    const float* cat_w  = (const float*)d_in[9];
    const float* cat_b  = (const float*)d_in[10];
    float* out = (float*)d_out;

    char* w = (char*)d_ws;
    size_t off = 0;
    auto alloc = [&](size_t bytes) { void* p = w + off; off += (bytes + 255) & ~(size_t)255; return p; };

    unsigned short* xbf    = (unsigned short*)alloc(10L * HW * 64 * 2);
    unsigned short* hbuf   = (unsigned short*)alloc(4L * HW * 128 * 2);
    unsigned short* comb   = (unsigned short*)alloc(4L * HW * 64 * 2);
    float*          omb    = (float*)alloc(4L * 216 * HW * 4);
    unsigned short* sampb  = (unsigned short*)alloc(4L * HW * 576 * 2);
    unsigned short* fusedb = (unsigned short*)alloc(4L * HW * 256 * 2);
    float*          cbufs  = (float*)alloc(4L * HW * 64 * 4);
    unsigned short* hseqb  = (unsigned short*)alloc(10L * HW * 128 * 2);
    unsigned short* Wf = (unsigned short*)alloc(9L * 64 * 2 * 128 * 2);
    unsigned short* Wo = (unsigned short*)alloc(9L * 256 * 2 * 64 * 2);
    unsigned short* Wc = (unsigned short*)alloc(9L * 256 * 2 * 128 * 2);
    unsigned short* Wk = (unsigned short*)alloc(9L * 64 * 2 * 128 * 2);
    unsigned short* W1 = (unsigned short*)alloc(128L * 2 * 576 * 2);

    dim3 blk(256);
    wexp3_kernel<<<dim3(288), blk, 0, stream>>>(fuse_w, Wf, 64, 64, 128);
    wexp3_kernel<<<dim3(576), blk, 0, stream>>>(om_w, Wo, 216, 256, 64);
    wexp3_kernel<<<dim3(1152), blk, 0, stream>>>(conv_w, Wc, 256, 256, 128);
    wexp3_kernel<<<dim3(288), blk, 0, stream>>>(cat_w, Wk, 64, 64, 128);
    wexp1_kernel<<<dim3(288), blk, 0, stream>>>(dcn_w, W1);
    xprep_kernel<<<dim3(23040), blk, 0, stream>>>(input, xbf);

    hipMemsetAsync(hbuf, 0, 4L * HW * 128 * 2, stream);
    hipMemsetAsync(cbufs, 0, 4L * HW * 64 * 4, stream);

    for (int s = 0; s < TT; ++s) {
        int t0 = s, t1 = TT - 1 - s;
        fuse_conv<<<dim3(144, 1, 4), blk, 0, stream>>>(
            xbf, hbuf, Wf, fuse_b, comb, t0, t1);
        om_conv<<<dim3(144, 1, 4), dim3(512), 0, stream>>>(
            comb, Wo, om_b, omb);
        dcn_sample_kernel<<<dim3(10368), blk, 0, stream>>>(hbuf, omb, sampb);
        conv1x1_hl<<<dim3(144, 4), blk, 0, stream>>>(sampb, W1, dcn_b, fusedb);
        big_conv_gates<<<dim3(144, 1, 4), dim3(512), 0, stream>>>(
            fusedb, Wc, conv_b, cbufs, hbuf, hseqb, t0, t1);
    }
    cat_conv<<<dim3(144, 1, 10), blk, 0, stream>>>(hseqb, Wk, cat_b, out);
}